// Round 1
// baseline (2052.845 us; speedup 1.0000x reference)
//
#include <hip/hip_runtime.h>
#include <hip/hip_bf16.h>

// ---------------------------------------------------------------------------
// GNN forward: 2x GCN (dense edge-weighted) + embedding-conv + AE MLP stack.
// Strategy: bf16 MFMA for all GEMMs (f32 accumulate), f32 BatchNorm stats.
// ---------------------------------------------------------------------------

typedef __attribute__((ext_vector_type(8))) short short8v;   // 8 x bf16 (4 VGPR)
typedef __attribute__((ext_vector_type(4))) float f32x4;

#define DEV __device__ __forceinline__

DEV short f2bf(float x) {                // RNE f32 -> bf16 (bit pattern as short)
    unsigned int u = __float_as_uint(x);
    u += 0x7fffu + ((u >> 16) & 1u);
    return (short)(u >> 16);
}
DEV float lrelu(float x) { return x >= 0.f ? x : 0.01f * x; }

// ---------------- f32 -> bf16 row-major with column zero-padding -----------
__global__ void k_f32_to_bf16_pad(const float* __restrict__ in, short* __restrict__ out,
                                  int R, int C, int Cp) {
    int n = R * Cp;
    for (int i = blockIdx.x * blockDim.x + threadIdx.x; i < n; i += gridDim.x * blockDim.x) {
        int r = i / Cp, c = i - r * Cp;
        out[i] = (c < C) ? f2bf(in[(size_t)r * C + c]) : (short)0;
    }
}

// ---------------- f32 [R][C] -> bf16 transposed [outR][outC], zero-padded ---
__global__ void k_transpose_bf16(const float* __restrict__ in, short* __restrict__ out,
                                 int R, int C, int outR, int outC) {
    __shared__ float tile[32][33];
    int cb = blockIdx.x * 32, rb = blockIdx.y * 32;
    int tx = threadIdx.x, ty = threadIdx.y;     // 32 x 8
#pragma unroll
    for (int i = 0; i < 32; i += 8) {
        int r = rb + ty + i, c = cb + tx;
        tile[ty + i][tx] = (r < R && c < C) ? in[(size_t)r * C + c] : 0.f;
    }
    __syncthreads();
#pragma unroll
    for (int i = 0; i < 32; i += 8) {
        int oc = cb + ty + i, orr = rb + tx;
        if (oc < outR && orr < outC)
            out[(size_t)oc * outC + orr] = f2bf(tile[tx][ty + i]);
    }
}

// ---------------- GEMM: C[M,N] = A[M,K] @ Bt[N,K]^T (+bias) ----------------
// A row-major bf16 (K mult of 64), Bt row-major bf16 (rows = Npad mult 128).
// 128x128 tile, BK=64, 4 waves each computing 64x64 via 16x16x32 bf16 MFMA.
__global__ __launch_bounds__(256)
void k_gemm_bt(const short* __restrict__ A, const short* __restrict__ Bt,
               float* __restrict__ Cout, const float* __restrict__ bias,
               int M, int Nreal, int K, int ldc) {
    __shared__ __align__(16) short As[128][72];   // +8 pad: 144B rows, 16B aligned
    __shared__ __align__(16) short Bs[128][72];
    const int tid  = threadIdx.x;
    const int row0 = blockIdx.x * 128, col0 = blockIdx.y * 128;
    const int w = tid >> 6, lane = tid & 63;
    const int wr = w >> 1, wc = w & 1;
    const int lr = lane & 15, lk = lane >> 4;
    const int sRow = tid >> 3;            // 0..31 (8 threads/row, 8 bf16 each)
    const int sCol = (tid & 7) * 8;

    f32x4 acc[4][4] = {};

    for (int k0 = 0; k0 < K; k0 += 64) {
#pragma unroll
        for (int p = 0; p < 4; ++p) {
            int r = p * 32 + sRow;
            short8v v = *reinterpret_cast<const short8v*>(&A[(size_t)(row0 + r) * K + k0 + sCol]);
            *reinterpret_cast<short8v*>(&As[r][sCol]) = v;
        }
#pragma unroll
        for (int p = 0; p < 4; ++p) {
            int r = p * 32 + sRow;
            short8v v = *reinterpret_cast<const short8v*>(&Bt[(size_t)(col0 + r) * K + k0 + sCol]);
            *reinterpret_cast<short8v*>(&Bs[r][sCol]) = v;
        }
        __syncthreads();
#pragma unroll
        for (int ks = 0; ks < 2; ++ks) {
            short8v a[4], b[4];
#pragma unroll
            for (int m = 0; m < 4; ++m)
                a[m] = *reinterpret_cast<const short8v*>(&As[wr * 64 + m * 16 + lr][ks * 32 + lk * 8]);
#pragma unroll
            for (int n = 0; n < 4; ++n)
                b[n] = *reinterpret_cast<const short8v*>(&Bs[wc * 64 + n * 16 + lr][ks * 32 + lk * 8]);
#pragma unroll
            for (int m = 0; m < 4; ++m)
#pragma unroll
                for (int n = 0; n < 4; ++n)
                    acc[m][n] = __builtin_amdgcn_mfma_f32_16x16x32_bf16(a[m], b[n], acc[m][n], 0, 0, 0);
        }
        __syncthreads();
    }
    // epilogue: C/D layout col = lane&15, row = (lane>>4)*4 + j  [m89-verified]
#pragma unroll
    for (int m = 0; m < 4; ++m) {
#pragma unroll
        for (int n = 0; n < 4; ++n) {
            int col = col0 + wc * 64 + n * 16 + lr;
            if (col < Nreal) {
                float bv = bias ? bias[col] : 0.f;
#pragma unroll
                for (int j = 0; j < 4; ++j) {
                    int row = row0 + wr * 64 + m * 16 + lk * 4 + j;
                    Cout[(size_t)row * ldc + col] = acc[m][n][j] + bv;
                }
            }
        }
    }
}

// ---------------- BatchNorm: column sums / sumsq (atomic partials) ---------
__global__ void k_col_stats(const float* __restrict__ X, float* __restrict__ sums,
                            float* __restrict__ sqs, int R, int C, int rowsPer) {
    int c = blockIdx.x * blockDim.x + threadIdx.x;
    if (c >= C) return;
    int r0 = blockIdx.y * rowsPer, r1 = min(r0 + rowsPer, R);
    float s = 0.f, q = 0.f;
    for (int r = r0; r < r1; ++r) { float v = X[(size_t)r * C + c]; s += v; q += v * v; }
    atomicAdd(&sums[c], s);
    atomicAdd(&sqs[c], q);
}

__global__ void k_bn_apply_f32(const float* __restrict__ X, const float* __restrict__ sums,
                               const float* __restrict__ sqs, const float* __restrict__ g,
                               const float* __restrict__ b, float* __restrict__ out,
                               int R, int C, float invR) {
    int n = R * C;
    for (int i = blockIdx.x * blockDim.x + threadIdx.x; i < n; i += gridDim.x * blockDim.x) {
        int c = i % C;
        float m = sums[c] * invR;
        float v = fmaxf(sqs[c] * invR - m * m, 0.f);
        float y = g[c] * (X[i] - m) * rsqrtf(v + 1e-5f) + b[c];
        out[i] = lrelu(y);
    }
}

__global__ void k_bn_apply_bf16(const float* __restrict__ X, const float* __restrict__ sums,
                                const float* __restrict__ sqs, const float* __restrict__ g,
                                const float* __restrict__ b, short* __restrict__ out,
                                int R, int C, int Cp, float invR) {
    int n = R * Cp;
    for (int i = blockIdx.x * blockDim.x + threadIdx.x; i < n; i += gridDim.x * blockDim.x) {
        int r = i / Cp, c = i - r * Cp;
        if (c < C) {
            float x = X[(size_t)r * C + c];
            float m = sums[c] * invR;
            float v = fmaxf(sqs[c] * invR - m * m, 0.f);
            float y = g[c] * (x - m) * rsqrtf(v + 1e-5f) + b[c];
            out[i] = f2bf(lrelu(y));
        } else out[i] = 0;
    }
}

// ---------------- conv path ------------------------------------------------
// Wp[c][o*8+kh] = W_conv[o][c][kh]
__global__ void k_build_wp(const float* __restrict__ Wc, float* __restrict__ Wp) {
    int i = blockIdx.x * blockDim.x + threadIdx.x;
    if (i >= 256000) return;
    int c = i >> 8, j = i & 255, o = j >> 3, kh = j & 7;
    Wp[i] = Wc[o * 8000 + c * 8 + kh];
}

// Per-batch: bucket-sort the 1000 symbols, S[s][j] = sum_{c in bucket s} Wp[c][j],
// then conv[o,h] = b_conv[o] + sum_{s,kh} S[s][o*8+kh]*emb[s][h+kh]; emit bf16
// row [3904] (K-padded) for the fc GEMM.
__global__ __launch_bounds__(256)
void k_conv_stage(const int* __restrict__ pemb, const float* __restrict__ Wp,
                  const float* __restrict__ emb, const float* __restrict__ b_conv,
                  short* __restrict__ conv_bf) {
    const int b = blockIdx.x, t = threadIdx.x;
    __shared__ int order[1000];
    __shared__ int cnt[26];
    __shared__ int bstart[27];
    __shared__ int cursor[26];
    __shared__ float embS[26 * 128];
    __shared__ float S[26 * 256];

    if (t < 26) cnt[t] = 0;
    __syncthreads();
    for (int c = t; c < 1000; c += 256) atomicAdd(&cnt[pemb[b * 1000 + c]], 1);
    for (int i = t; i < 26 * 128; i += 256) embS[i] = emb[i];
    __syncthreads();
    if (t == 0) {
        int run = 0;
        for (int s = 0; s < 26; ++s) { bstart[s] = run; cursor[s] = run; run += cnt[s]; }
        bstart[26] = run;
    }
    __syncthreads();
    for (int c = t; c < 1000; c += 256) {
        int s = pemb[b * 1000 + c];
        int pos = atomicAdd(&cursor[s], 1);
        order[pos] = c;
    }
    __syncthreads();
    // phase 1: thread t owns column j=t of S; coalesced 1KB Wp row scans
    for (int s = 0; s < 26; ++s) {
        float a = 0.f;
        int p1 = bstart[s + 1];
        for (int p = bstart[s]; p < p1; ++p) a += Wp[order[p] * 256 + t];
        S[s * 256 + t] = a;
    }
    __syncthreads();
    // phase 2: conv + bias -> bf16
    for (int oi = t; oi < 3872; oi += 256) {
        int o = oi / 121, h = oi - o * 121;
        float acc = b_conv[o];
        for (int s = 0; s < 26; ++s) {
#pragma unroll
            for (int kh = 0; kh < 8; ++kh)
                acc += S[s * 256 + o * 8 + kh] * embS[s * 128 + h + kh];
        }
        conv_bf[(size_t)b * 3904 + oi] = f2bf(acc);
    }
    if (t < 32) conv_bf[(size_t)b * 3904 + 3872 + t] = 0;   // K-pad
}

// ---------------- feature assembly ----------------------------------------
__global__ void k_assemble(const float* __restrict__ d_vecs, const float* __restrict__ E,
                           const float* __restrict__ xt, const float* __restrict__ G,
                           const int* __restrict__ d_index, const int* __restrict__ p_index,
                           float* __restrict__ feat) {
    int n = 2048 * 2476;
    for (int i = blockIdx.x * blockDim.x + threadIdx.x; i < n; i += gridDim.x * blockDim.x) {
        int b = i / 2476, c = i - b * 2476;
        float v;
        if (c < 300)        v = d_vecs[b * 300 + c];
        else if (c < 1324)  v = E[(size_t)d_index[b] * 1024 + (c - 300)];
        else if (c < 1452)  v = xt[b * 128 + (c - 1324)];
        else                v = G[(size_t)p_index[b] * 1024 + (c - 1452)];
        feat[i] = v;
    }
}

// ---------------- final y = o1post @ W_o2 + b_o2 ---------------------------
__global__ void k_final_y(const float* __restrict__ o1post, const float* __restrict__ W_o2,
                          const float* __restrict__ b_o2, float* __restrict__ y, int B) {
    int gt = blockIdx.x * blockDim.x + threadIdx.x;
    int wid = gt >> 6, lane = gt & 63;
    if (wid >= B) return;
    float v = o1post[wid * 64 + lane] * W_o2[lane];
#pragma unroll
    for (int off = 32; off; off >>= 1) v += __shfl_down(v, off);
    if (lane == 0) y[wid] = v + b_o2[0];
}

// ===========================================================================
extern "C" void kernel_launch(void* const* d_in, const int* in_sizes, int n_in,
                              void* d_out, int out_size, void* d_ws, size_t ws_size,
                              hipStream_t stream) {
    // --- inputs (setup_inputs dict order) ---
    const int*   d_index = (const int*)  d_in[0];
    const int*   p_index = (const int*)  d_in[1];
    const int*   p_emb   = (const int*)  d_in[2];
    const float* d_vecs  = (const float*)d_in[3];
    const float* d_ecfps = (const float*)d_in[4];
    const float* d_ew    = (const float*)d_in[5];
    const float* p_gos   = (const float*)d_in[6];
    const float* p_ew    = (const float*)d_in[7];
    const float* emb     = (const float*)d_in[8];
    const float* W_ge    = (const float*)d_in[9];
    const float* b_ge    = (const float*)d_in[10];
    const float* W_gg    = (const float*)d_in[11];
    const float* b_gg    = (const float*)d_in[12];
    const float* g_n1    = (const float*)d_in[13];
    const float* b_n1    = (const float*)d_in[14];
    const float* W_conv  = (const float*)d_in[15];
    const float* b_conv  = (const float*)d_in[16];
    const float* W_fc    = (const float*)d_in[17];
    const float* b_fc    = (const float*)d_in[18];
    const float* W_e1    = (const float*)d_in[19];
    const float* b_e1    = (const float*)d_in[20];
    const float* g_e1    = (const float*)d_in[21];
    const float* be_e1   = (const float*)d_in[22];
    const float* W_e2    = (const float*)d_in[23];
    const float* b_e2    = (const float*)d_in[24];
    const float* g_e2    = (const float*)d_in[25];
    const float* be_e2   = (const float*)d_in[26];
    const float* W_d1    = (const float*)d_in[27];
    const float* b_d1    = (const float*)d_in[28];
    const float* g_d1    = (const float*)d_in[29];
    const float* be_d1   = (const float*)d_in[30];
    const float* W_d2    = (const float*)d_in[31];
    const float* b_d2    = (const float*)d_in[32];
    const float* g_d2    = (const float*)d_in[33];
    const float* be_d2   = (const float*)d_in[34];
    const float* W_o1    = (const float*)d_in[35];
    const float* b_o1    = (const float*)d_in[36];
    const float* g_o1    = (const float*)d_in[37];
    const float* be_o1   = (const float*)d_in[38];
    const float* W_o2    = (const float*)d_in[39];
    const float* b_o2    = (const float*)d_in[40];

    // --- outputs: (y[2048], dec[2048*2476], feature[2048*2476]) ---
    float* outY    = (float*)d_out;
    float* outDec  = outY + 2048;
    float* outFeat = outDec + (size_t)2048 * 2476;

    // --- workspace carve-out (~162 MB) ---
    char* W = (char*)d_ws;
    size_t cur = 0;
    auto take = [&](size_t bytes) -> size_t {
        size_t r = cur; cur += (bytes + 255) & ~(size_t)255; return r;
    };
    float* stats   = (float*)(W + take(17880 * 4));
    short* bufX    = (short*)(W + take((size_t)4096 * 2048 * 2));  // ecfps_bf / gos_bf
    short* ew_bf   = (short*)(W + take((size_t)4096 * 4096 * 2));  // d_ew / p_ew
    short* feat_bf = (short*)(W + take((size_t)2048 * 2496 * 2));
    short* enc1_bf = (short*)(W + take((size_t)2048 * 2048 * 2));
    short* enc_bf  = (short*)(W + take((size_t)2048 * 256 * 2));
    short* dec1_bf = (short*)(W + take((size_t)2048 * 2048 * 2));
    short* conv_bf = (short*)(W + take((size_t)2048 * 3904 * 2));
    short* bufWT   = (short*)(W + take((size_t)2560 * 2048 * 2));  // all B^T operands (seq reuse)
    float* bufT    = (float*)(W + take((size_t)2048 * 2476 * 4));  // raw GEMM outs (seq reuse)
    float* bufE    = (float*)(W + take((size_t)4096 * 1024 * 4));  // drug GCN post-BN
    float* bufG    = (float*)(W + take((size_t)4096 * 1024 * 4));  // protein GCN post-BN
    float* xt      = (float*)(W + take((size_t)2048 * 128 * 4));
    float* o1post  = (float*)(W + take((size_t)2048 * 64 * 4));
    float* Wp      = (float*)(W + take((size_t)1000 * 256 * 4));

    // stats slices
    float* sD  = stats,        *qD  = sD + 1024;
    float* sP  = qD + 1024,    *qP  = sP + 1024;
    float* sE1 = qP + 1024,    *qE1 = sE1 + 2048;
    float* sE2 = qE1 + 2048,   *qE2 = sE2 + 256;
    float* sD1 = qE2 + 256,    *qD1 = sD1 + 2048;
    float* sD2 = qD1 + 2048,   *qD2 = sD2 + 2476;
    float* sO1 = qD2 + 2476,   *qO1 = sO1 + 64;
    (void)qO1;
    hipMemsetAsync(stats, 0, 17880 * 4, stream);

    auto gsb = [](long n) { long b = (n + 255) / 256; if (b > 4096) b = 4096; return dim3((unsigned)b); };
    auto CVT = [&](const float* in, short* out, int R, int C, int Cp) {
        k_f32_to_bf16_pad<<<gsb((long)R * Cp), 256, 0, stream>>>(in, out, R, C, Cp);
    };
    auto XPOSE = [&](const float* in, short* out, int R, int C, int oR, int oC) {
        k_transpose_bf16<<<dim3(oR / 32, oC / 32), dim3(32, 8), 0, stream>>>(in, out, R, C, oR, oC);
    };
    auto GEMM = [&](const short* A, const short* Bt, float* Co, const float* bias,
                    int M, int Npad, int Nreal, int K, int ldc) {
        k_gemm_bt<<<dim3(M / 128, Npad / 128), 256, 0, stream>>>(A, Bt, Co, bias, M, Nreal, K, ldc);
    };
    auto STATS = [&](const float* X, float* s, float* q, int R, int C) {
        k_col_stats<<<dim3((C + 255) / 256, R / 256), 256, 0, stream>>>(X, s, q, R, C, 256);
    };

    // ---------------- drug GCN ----------------
    CVT(d_ecfps, bufX, 4096, 1024, 1024);
    XPOSE(W_ge, bufWT, 1024, 1024, 1024, 1024);
    GEMM(bufX, bufWT, bufT, nullptr, 4096, 1024, 1024, 1024, 1024);        // T1
    XPOSE(bufT, bufWT, 4096, 1024, 1024, 4096);                            // T1^T bf16
    CVT(d_ew, ew_bf, 4096, 4096, 4096);
    GEMM(ew_bf, bufWT, bufE, b_ge, 4096, 1024, 1024, 4096, 1024);          // T2
    STATS(bufE, sD, qD, 4096, 1024);
    k_bn_apply_f32<<<gsb(4096L * 1024), 256, 0, stream>>>(bufE, sD, qD, g_n1, b_n1, bufE, 4096, 1024, 1.f / 4096);

    // ---------------- protein GCN ----------------
    CVT(p_gos, bufX, 4096, 2048, 2048);
    XPOSE(W_gg, bufWT, 2048, 1024, 1024, 2048);
    GEMM(bufX, bufWT, bufT, nullptr, 4096, 1024, 1024, 2048, 1024);        // T3
    XPOSE(bufT, bufWT, 4096, 1024, 1024, 4096);                            // T3^T
    CVT(p_ew, ew_bf, 4096, 4096, 4096);
    GEMM(ew_bf, bufWT, bufG, b_gg, 4096, 1024, 1024, 4096, 1024);          // T4
    STATS(bufG, sP, qP, 4096, 1024);
    k_bn_apply_f32<<<gsb(4096L * 1024), 256, 0, stream>>>(bufG, sP, qP, g_n1, b_n1, bufG, 4096, 1024, 1.f / 4096);

    // ---------------- conv path ----------------
    k_build_wp<<<dim3(1000), 256, 0, stream>>>(W_conv, Wp);
    k_conv_stage<<<dim3(2048), 256, 0, stream>>>(p_emb, Wp, emb, b_conv, conv_bf);
    XPOSE(W_fc, bufWT, 3872, 128, 128, 3904);
    GEMM(conv_bf, bufWT, xt, b_fc, 2048, 128, 128, 3904, 128);             // xt

    // ---------------- feature ----------------
    k_assemble<<<gsb(2048L * 2476), 256, 0, stream>>>(d_vecs, bufE, xt, bufG, d_index, p_index, outFeat);
    CVT(outFeat, feat_bf, 2048, 2476, 2496);

    // ---------------- encoder ----------------
    XPOSE(W_e1, bufWT, 2476, 2048, 2048, 2496);
    GEMM(feat_bf, bufWT, bufT, b_e1, 2048, 2048, 2048, 2496, 2048);        // enc1 raw
    STATS(bufT, sE1, qE1, 2048, 2048);
    k_bn_apply_bf16<<<gsb(2048L * 2048), 256, 0, stream>>>(bufT, sE1, qE1, g_e1, be_e1, enc1_bf, 2048, 2048, 2048, 1.f / 2048);

    XPOSE(W_e2, bufWT, 2048, 256, 256, 2048);
    GEMM(enc1_bf, bufWT, bufT, b_e2, 2048, 256, 256, 2048, 256);           // enc2 raw
    STATS(bufT, sE2, qE2, 2048, 256);
    k_bn_apply_bf16<<<gsb(2048L * 256), 256, 0, stream>>>(bufT, sE2, qE2, g_e2, be_e2, enc_bf, 2048, 256, 256, 1.f / 2048);

    // ---------------- decoder ----------------
    XPOSE(W_d1, bufWT, 256, 2048, 2048, 256);
    GEMM(enc_bf, bufWT, bufT, b_d1, 2048, 2048, 2048, 256, 2048);          // dec1 raw
    STATS(bufT, sD1, qD1, 2048, 2048);
    k_bn_apply_bf16<<<gsb(2048L * 2048), 256, 0, stream>>>(bufT, sD1, qD1, g_d1, be_d1, dec1_bf, 2048, 2048, 2048, 1.f / 2048);

    XPOSE(W_d2, bufWT, 2048, 2476, 2560, 2048);
    GEMM(dec1_bf, bufWT, bufT, b_d2, 2048, 2560, 2476, 2048, 2476);        // dec2 raw
    STATS(bufT, sD2, qD2, 2048, 2476);
    k_bn_apply_f32<<<gsb(2048L * 2476), 256, 0, stream>>>(bufT, sD2, qD2, g_d2, be_d2, outDec, 2048, 2476, 1.f / 2048);

    // ---------------- output head ----------------
    XPOSE(W_o1, bufWT, 256, 64, 128, 256);
    GEMM(enc_bf, bufWT, bufT, b_o1, 2048, 128, 64, 256, 64);               // o1 raw
    STATS(bufT, sO1, qO1, 2048, 64);
    k_bn_apply_f32<<<gsb(2048L * 64), 256, 0, stream>>>(bufT, sO1, qO1, g_o1, be_o1, o1post, 2048, 64, 1.f / 2048);
    k_final_y<<<dim3(512), 256, 0, stream>>>(o1post, W_o2, b_o2, outY, 2048);

    (void)in_sizes; (void)n_in; (void)out_size; (void)ws_size;
}

// Round 2
// 1372.127 us; speedup vs baseline: 1.4961x; 1.4961x over previous
//
#include <hip/hip_runtime.h>
#include <hip/hip_bf16.h>

// ---------------------------------------------------------------------------
// GNN forward: 2x GCN (dense edge-weighted) + embedding-conv + AE MLP stack.
// R2: conv path replaced by algebraic R-gather; GEMMs use global_load_lds
// double-buffered 2-phase with BN=64 tiles for occupancy.
// ---------------------------------------------------------------------------

typedef __attribute__((ext_vector_type(8))) short short8v;   // 8 x bf16
typedef __attribute__((ext_vector_type(4))) float f32x4;

#define DEV __device__ __forceinline__

DEV short f2bf(float x) {                // RNE f32 -> bf16
    unsigned int u = __float_as_uint(x);
    u += 0x7fffu + ((u >> 16) & 1u);
    return (short)(u >> 16);
}
DEV float bf2f(short v) { return __uint_as_float(((unsigned int)(unsigned short)v) << 16); }
DEV float lrelu(float x) { return x >= 0.f ? x : 0.01f * x; }

DEV void gload_lds16(const short* gp, short* lds_base_uniform) {
    __builtin_amdgcn_global_load_lds(
        (const __attribute__((address_space(1))) unsigned int*)gp,
        (__attribute__((address_space(3))) unsigned int*)lds_base_uniform,
        16, 0, 0);
}

// ---------------- f32 -> bf16 row-major with column zero-padding -----------
__global__ void k_f32_to_bf16_pad(const float* __restrict__ in, short* __restrict__ out,
                                  int R, int C, int Cp) {
    int n = R * Cp;
    for (int i = blockIdx.x * blockDim.x + threadIdx.x; i < n; i += gridDim.x * blockDim.x) {
        int r = i / Cp, c = i - r * Cp;
        out[i] = (c < C) ? f2bf(in[(size_t)r * C + c]) : (short)0;
    }
}

// ---------------- f32 [R][C] -> bf16 transposed [outR][outC], zero-padded ---
__global__ void k_transpose_bf16(const float* __restrict__ in, short* __restrict__ out,
                                 int R, int C, int outR, int outC) {
    __shared__ float tile[32][33];
    int cb = blockIdx.x * 32, rb = blockIdx.y * 32;
    int tx = threadIdx.x, ty = threadIdx.y;     // 32 x 8
#pragma unroll
    for (int i = 0; i < 32; i += 8) {
        int r = rb + ty + i, c = cb + tx;
        tile[ty + i][tx] = (r < R && c < C) ? in[(size_t)r * C + c] : 0.f;
    }
    __syncthreads();
#pragma unroll
    for (int i = 0; i < 32; i += 8) {
        int oc = cb + ty + i, orr = rb + tx;
        if (oc < outR && orr < outC)
            out[(size_t)oc * outC + orr] = f2bf(tile[tx][ty + i]);
    }
}

// ---------------- GEMM: C[M,N] = A[M,K] @ Bt[N,K]^T (+bias) ----------------
// global_load_lds staging into linear LDS, double-buffered, 1 barrier/K-step.
// 256 threads = 4 waves in 2x2; wave tile (BM/2)x(BN/2); 16x16x32 bf16 MFMA.
template<int BM, int BN, bool OBF>
__global__ __launch_bounds__(256)
void k_gemm(const short* __restrict__ A, const short* __restrict__ Bt,
            void* __restrict__ Cout, const float* __restrict__ bias,
            int M, int Nreal, int K, int ldc) {
    __shared__ __align__(16) short As[2][BM * 64];
    __shared__ __align__(16) short Bs[2][BN * 64];
    const int tid  = threadIdx.x;
    const int lane = tid & 63, w = tid >> 6;
    const int row0 = blockIdx.x * BM, col0 = blockIdx.y * BN;
    const int wr = w >> 1, wc = w & 1;
    const int lr = lane & 15, lk = lane >> 4;
    const int lrow = lane >> 3, lcol = (lane & 7) * 8;   // staging lane map
    constexpr int MR = BM / 32, NR = BN / 32;

    f32x4 acc[MR][NR] = {};

    auto stage = [&](int buf, int k0) {
#pragma unroll
        for (int i = 0; i < BM / 32; ++i) {
            int r0 = (w * (BM / 32) + i) * 8;
            gload_lds16(&A[(size_t)(row0 + r0 + lrow) * K + k0 + lcol], &As[buf][r0 * 64]);
        }
#pragma unroll
        for (int i = 0; i < BN / 32; ++i) {
            int r0 = (w * (BN / 32) + i) * 8;
            gload_lds16(&Bt[(size_t)(col0 + r0 + lrow) * K + k0 + lcol], &Bs[buf][r0 * 64]);
        }
    };

    const int nt = K >> 6;
    stage(0, 0);
    __syncthreads();                       // drains vmcnt(0): buf0 ready
    for (int t = 0; t < nt; ++t) {
        int cur = t & 1;
        if (t + 1 < nt) stage(cur ^ 1, (t + 1) << 6);   // async, in flight
#pragma unroll
        for (int ks = 0; ks < 2; ++ks) {
            short8v a[MR], b[NR];
#pragma unroll
            for (int m = 0; m < MR; ++m)
                a[m] = *reinterpret_cast<const short8v*>(&As[cur][(wr * (BM / 2) + m * 16 + lr) * 64 + ks * 32 + lk * 8]);
#pragma unroll
            for (int n = 0; n < NR; ++n)
                b[n] = *reinterpret_cast<const short8v*>(&Bs[cur][(wc * (BN / 2) + n * 16 + lr) * 64 + ks * 32 + lk * 8]);
#pragma unroll
            for (int m = 0; m < MR; ++m)
#pragma unroll
                for (int n = 0; n < NR; ++n)
                    acc[m][n] = __builtin_amdgcn_mfma_f32_16x16x32_bf16(a[m], b[n], acc[m][n], 0, 0, 0);
        }
        __syncthreads();                   // next buf staged + all reads done
    }
    // epilogue: C/D layout col = lane&15, row = (lane>>4)*4 + j
#pragma unroll
    for (int m = 0; m < MR; ++m) {
#pragma unroll
        for (int n = 0; n < NR; ++n) {
            int col = col0 + wc * (BN / 2) + n * 16 + lr;
            if (col < Nreal) {
                float bv = bias ? bias[col] : 0.f;
#pragma unroll
                for (int j = 0; j < 4; ++j) {
                    int row = row0 + wr * (BM / 2) + m * 16 + lk * 4 + j;
                    float v = acc[m][n][j] + bv;
                    if (OBF) ((short*)Cout)[(size_t)row * ldc + col] = f2bf(v);
                    else     ((float*)Cout)[(size_t)row * ldc + col] = v;
                }
            }
        }
    }
    (void)M;
}

// ---------------- BatchNorm: column sums / sumsq (atomic partials) ---------
__global__ void k_col_stats(const float* __restrict__ X, float* __restrict__ sums,
                            float* __restrict__ sqs, int R, int C, int rowsPer) {
    int c = blockIdx.x * blockDim.x + threadIdx.x;
    if (c >= C) return;
    int r0 = blockIdx.y * rowsPer, r1 = min(r0 + rowsPer, R);
    float s = 0.f, q = 0.f;
    for (int r = r0; r < r1; ++r) { float v = X[(size_t)r * C + c]; s += v; q += v * v; }
    atomicAdd(&sums[c], s);
    atomicAdd(&sqs[c], q);
}

__global__ void k_bn_apply_f32(const float* __restrict__ X, const float* __restrict__ sums,
                               const float* __restrict__ sqs, const float* __restrict__ g,
                               const float* __restrict__ b, float* __restrict__ out,
                               int R, int C, float invR) {
    int n = R * C;
    for (int i = blockIdx.x * blockDim.x + threadIdx.x; i < n; i += gridDim.x * blockDim.x) {
        int c = i % C;
        float m = sums[c] * invR;
        float v = fmaxf(sqs[c] * invR - m * m, 0.f);
        float y = g[c] * (X[i] - m) * rsqrtf(v + 1e-5f) + b[c];
        out[i] = lrelu(y);
    }
}

__global__ void k_bn_apply_bf16(const float* __restrict__ X, const float* __restrict__ sums,
                                const float* __restrict__ sqs, const float* __restrict__ g,
                                const float* __restrict__ b, short* __restrict__ out,
                                int R, int C, int Cp, float invR) {
    int n = R * Cp;
    for (int i = blockIdx.x * blockDim.x + threadIdx.x; i < n; i += gridDim.x * blockDim.x) {
        int r = i / Cp, c = i - r * Cp;
        if (c < C) {
            float x = X[(size_t)r * C + c];
            float m = sums[c] * invR;
            float v = fmaxf(sqs[c] * invR - m * m, 0.f);
            float y = g[c] * (x - m) * rsqrtf(v + 1e-5f) + b[c];
            out[i] = f2bf(lrelu(y));
        } else out[i] = 0;
    }
}

// ---------------- conv path (algebraic) ------------------------------------
// Wp_bf[c][o*8+kh] = W_conv[o][c][kh], rows 1000..1023 zero.  [1024][256]
__global__ void k_build_wp_bf(const float* __restrict__ Wc, short* __restrict__ Wp) {
    int i = blockIdx.x * blockDim.x + threadIdx.x;
    if (i >= 1024 * 256) return;
    int c = i >> 8, j = i & 255, o = j >> 3, kh = j & 7;
    Wp[i] = (c < 1000) ? f2bf(Wc[o * 8000 + c * 8 + kh]) : (short)0;
}

// M2t[(s*128+f)][o*8+kh] = sum_h emb[s][h+kh] * W_fc[o*121+h][f]   [3328][256]
__global__ __launch_bounds__(256)
void k_build_m2t(const float* __restrict__ emb, const float* __restrict__ W_fc,
                 short* __restrict__ M2t) {
    int s = blockIdx.x >> 5, o = blockIdx.x & 31;   // 26*32 blocks
    __shared__ float embS[128];
    int t = threadIdx.x;
    if (t < 128) embS[t] = emb[s * 128 + t];
    __syncthreads();
    int f = t & 127;
    int khBase = (t >> 7) * 4;
#pragma unroll
    for (int i = 0; i < 4; ++i) {
        int kh = khBase + i;
        float acc = 0.f;
        for (int h = 0; h < 121; ++h)
            acc += embS[h + kh] * W_fc[(o * 121 + h) * 128 + f];
        M2t[((size_t)(s * 128 + f)) * 256 + o * 8 + kh] = f2bf(acc);
    }
}

// Cf[f] += b_conv[o] * sum_h W_fc[o*121+h][f]   (Cf pre-zeroed)
__global__ void k_build_cf(const float* __restrict__ W_fc, const float* __restrict__ b_conv,
                           float* __restrict__ Cf) {
    int o = blockIdx.x, f = threadIdx.x;   // 32 blocks x 128
    float acc = 0.f;
    for (int h = 0; h < 121; ++h) acc += W_fc[(o * 121 + h) * 128 + f];
    atomicAdd(&Cf[f], acc * b_conv[o]);
}

// xt[b][f] = b_fc[f] + Cf[f] + sum_c Rbf[c][pemb[b,c]*128+f]
__global__ __launch_bounds__(256)
void k_gather_xt(const int* __restrict__ pemb, const short* __restrict__ Rbf,
                 const float* __restrict__ Cf, const float* __restrict__ b_fc,
                 float* __restrict__ xt) {
    const int b = blockIdx.x, t = threadIdx.x;
    __shared__ int sS[1000];
    __shared__ float red[256];
    for (int c = t; c < 1000; c += 256) sS[c] = pemb[b * 1000 + c];
    __syncthreads();
    const int f = t & 127, half = t >> 7;
    float acc = 0.f;
    const int c0 = half * 500;
#pragma unroll 4
    for (int c = c0; c < c0 + 500; ++c) {
        int s = sS[c];
        acc += bf2f(Rbf[((size_t)c * 26 + s) * 128 + f]);
    }
    red[t] = acc;
    __syncthreads();
    if (t < 128) xt[b * 128 + f] = red[f] + red[128 + f] + Cf[f] + b_fc[f];
}

// ---------------- feature assembly ----------------------------------------
__global__ void k_assemble(const float* __restrict__ d_vecs, const float* __restrict__ E,
                           const float* __restrict__ xt, const float* __restrict__ G,
                           const int* __restrict__ d_index, const int* __restrict__ p_index,
                           float* __restrict__ feat) {
    int n = 2048 * 2476;
    for (int i = blockIdx.x * blockDim.x + threadIdx.x; i < n; i += gridDim.x * blockDim.x) {
        int b = i / 2476, c = i - b * 2476;
        float v;
        if (c < 300)        v = d_vecs[b * 300 + c];
        else if (c < 1324)  v = E[(size_t)d_index[b] * 1024 + (c - 300)];
        else if (c < 1452)  v = xt[b * 128 + (c - 1324)];
        else                v = G[(size_t)p_index[b] * 1024 + (c - 1452)];
        feat[i] = v;
    }
}

// ---------------- final y = o1post @ W_o2 + b_o2 ---------------------------
__global__ void k_final_y(const float* __restrict__ o1post, const float* __restrict__ W_o2,
                          const float* __restrict__ b_o2, float* __restrict__ y, int B) {
    int gt = blockIdx.x * blockDim.x + threadIdx.x;
    int wid = gt >> 6, lane = gt & 63;
    if (wid >= B) return;
    float v = o1post[wid * 64 + lane] * W_o2[lane];
#pragma unroll
    for (int off = 32; off; off >>= 1) v += __shfl_down(v, off);
    if (lane == 0) y[wid] = v + b_o2[0];
}

// ===========================================================================
extern "C" void kernel_launch(void* const* d_in, const int* in_sizes, int n_in,
                              void* d_out, int out_size, void* d_ws, size_t ws_size,
                              hipStream_t stream) {
    const int*   d_index = (const int*)  d_in[0];
    const int*   p_index = (const int*)  d_in[1];
    const int*   p_emb   = (const int*)  d_in[2];
    const float* d_vecs  = (const float*)d_in[3];
    const float* d_ecfps = (const float*)d_in[4];
    const float* d_ew    = (const float*)d_in[5];
    const float* p_gos   = (const float*)d_in[6];
    const float* p_ew    = (const float*)d_in[7];
    const float* emb     = (const float*)d_in[8];
    const float* W_ge    = (const float*)d_in[9];
    const float* b_ge    = (const float*)d_in[10];
    const float* W_gg    = (const float*)d_in[11];
    const float* b_gg    = (const float*)d_in[12];
    const float* g_n1    = (const float*)d_in[13];
    const float* b_n1    = (const float*)d_in[14];
    const float* W_conv  = (const float*)d_in[15];
    const float* b_conv  = (const float*)d_in[16];
    const float* W_fc    = (const float*)d_in[17];
    const float* b_fc    = (const float*)d_in[18];
    const float* W_e1    = (const float*)d_in[19];
    const float* b_e1    = (const float*)d_in[20];
    const float* g_e1    = (const float*)d_in[21];
    const float* be_e1   = (const float*)d_in[22];
    const float* W_e2    = (const float*)d_in[23];
    const float* b_e2    = (const float*)d_in[24];
    const float* g_e2    = (const float*)d_in[25];
    const float* be_e2   = (const float*)d_in[26];
    const float* W_d1    = (const float*)d_in[27];
    const float* b_d1    = (const float*)d_in[28];
    const float* g_d1    = (const float*)d_in[29];
    const float* be_d1   = (const float*)d_in[30];
    const float* W_d2    = (const float*)d_in[31];
    const float* b_d2    = (const float*)d_in[32];
    const float* g_d2    = (const float*)d_in[33];
    const float* be_d2   = (const float*)d_in[34];
    const float* W_o1    = (const float*)d_in[35];
    const float* b_o1    = (const float*)d_in[36];
    const float* g_o1    = (const float*)d_in[37];
    const float* be_o1   = (const float*)d_in[38];
    const float* W_o2    = (const float*)d_in[39];
    const float* b_o2    = (const float*)d_in[40];

    float* outY    = (float*)d_out;
    float* outDec  = outY + 2048;
    float* outFeat = outDec + (size_t)2048 * 2476;

    char* W = (char*)d_ws;
    size_t cur = 0;
    auto take = [&](size_t bytes) -> size_t {
        size_t r = cur; cur += (bytes + 255) & ~(size_t)255; return r;
    };
    float* stats   = (float*)(W + take(18008 * 4));                // stats + Cf
    short* bufX    = (short*)(W + take((size_t)4096 * 2048 * 2));
    short* ew_bf   = (short*)(W + take((size_t)4096 * 4096 * 2));
    short* feat_bf = (short*)(W + take((size_t)2048 * 2496 * 2));
    short* enc1_bf = (short*)(W + take((size_t)2048 * 2048 * 2));
    short* enc_bf  = (short*)(W + take((size_t)2048 * 256 * 2));
    short* dec1_bf = (short*)(W + take((size_t)2048 * 2048 * 2));
    short* bufWT   = (short*)(W + take((size_t)2560 * 2048 * 2));
    float* bufT    = (float*)(W + take((size_t)2048 * 2476 * 4));
    float* bufE    = (float*)(W + take((size_t)4096 * 1024 * 4));
    float* bufG    = (float*)(W + take((size_t)4096 * 1024 * 4));
    float* xt      = (float*)(W + take((size_t)2048 * 128 * 4));
    float* o1post  = (float*)(W + take((size_t)2048 * 64 * 4));
    short* Wp_bf   = (short*)(W + take((size_t)1024 * 256 * 2));
    short* M2t     = (short*)(W + take((size_t)3328 * 256 * 2));
    short* Rbf     = (short*)(W + take((size_t)1024 * 3328 * 2));

    float* sD  = stats,        *qD  = sD + 1024;
    float* sP  = qD + 1024,    *qP  = sP + 1024;
    float* sE1 = qP + 1024,    *qE1 = sE1 + 2048;
    float* sE2 = qE1 + 2048,   *qE2 = sE2 + 256;
    float* sD1 = qE2 + 256,    *qD1 = sD1 + 2048;
    float* sD2 = qD1 + 2048,   *qD2 = sD2 + 2476;
    float* sO1 = qD2 + 2476,   *qO1 = sO1 + 64;
    float* Cf  = qO1 + 64;
    hipMemsetAsync(stats, 0, 18008 * 4, stream);

    auto gsb = [](long n) { long b = (n + 255) / 256; if (b > 4096) b = 4096; return dim3((unsigned)b); };
    auto CVT = [&](const float* in, short* out, int R, int C, int Cp) {
        k_f32_to_bf16_pad<<<gsb((long)R * Cp), 256, 0, stream>>>(in, out, R, C, Cp);
    };
    auto XPOSE = [&](const float* in, short* out, int R, int C, int oR, int oC) {
        k_transpose_bf16<<<dim3(oR / 32, oC / 32), dim3(32, 8), 0, stream>>>(in, out, R, C, oR, oC);
    };
    auto GEMM = [&](const short* A, const short* Bt, float* Co, const float* bias,
                    int M, int Npad, int Nreal, int K, int ldc) {
        k_gemm<128, 64, false><<<dim3(M / 128, Npad / 64), 256, 0, stream>>>(A, Bt, Co, bias, M, Nreal, K, ldc);
    };
    auto STATS = [&](const float* X, float* s, float* q, int R, int C) {
        k_col_stats<<<dim3((C + 255) / 256, R / 256), 256, 0, stream>>>(X, s, q, R, C, 256);
    };

    // ---------------- conv path (independent; launch first) ----------------
    k_build_wp_bf<<<dim3(1024), 256, 0, stream>>>(W_conv, Wp_bf);
    k_build_m2t<<<dim3(26 * 32), 256, 0, stream>>>(emb, W_fc, M2t);
    k_build_cf<<<dim3(32), 128, 0, stream>>>(W_fc, b_conv, Cf);
    k_gemm<128, 64, true><<<dim3(1024 / 128, 3328 / 64), 256, 0, stream>>>(
        Wp_bf, M2t, (void*)Rbf, nullptr, 1024, 3328, 256, 3328);
    k_gather_xt<<<dim3(2048), 256, 0, stream>>>(p_emb, Rbf, Cf, b_fc, xt);

    // ---------------- drug GCN ----------------
    CVT(d_ecfps, bufX, 4096, 1024, 1024);
    XPOSE(W_ge, bufWT, 1024, 1024, 1024, 1024);
    GEMM(bufX, bufWT, bufT, nullptr, 4096, 1024, 1024, 1024, 1024);        // T1
    XPOSE(bufT, bufWT, 4096, 1024, 1024, 4096);
    CVT(d_ew, ew_bf, 4096, 4096, 4096);
    GEMM(ew_bf, bufWT, bufE, b_ge, 4096, 1024, 1024, 4096, 1024);          // T2
    STATS(bufE, sD, qD, 4096, 1024);
    k_bn_apply_f32<<<gsb(4096L * 1024), 256, 0, stream>>>(bufE, sD, qD, g_n1, b_n1, bufE, 4096, 1024, 1.f / 4096);

    // ---------------- protein GCN ----------------
    CVT(p_gos, bufX, 4096, 2048, 2048);
    XPOSE(W_gg, bufWT, 2048, 1024, 1024, 2048);
    GEMM(bufX, bufWT, bufT, nullptr, 4096, 1024, 1024, 2048, 1024);        // T3
    XPOSE(bufT, bufWT, 4096, 1024, 1024, 4096);
    CVT(p_ew, ew_bf, 4096, 4096, 4096);
    GEMM(ew_bf, bufWT, bufG, b_gg, 4096, 1024, 1024, 4096, 1024);          // T4
    STATS(bufG, sP, qP, 4096, 1024);
    k_bn_apply_f32<<<gsb(4096L * 1024), 256, 0, stream>>>(bufG, sP, qP, g_n1, b_n1, bufG, 4096, 1024, 1.f / 4096);

    // ---------------- feature ----------------
    k_assemble<<<gsb(2048L * 2476), 256, 0, stream>>>(d_vecs, bufE, xt, bufG, d_index, p_index, outFeat);
    CVT(outFeat, feat_bf, 2048, 2476, 2496);

    // ---------------- encoder ----------------
    XPOSE(W_e1, bufWT, 2476, 2048, 2048, 2496);
    GEMM(feat_bf, bufWT, bufT, b_e1, 2048, 2048, 2048, 2496, 2048);        // enc1 raw
    STATS(bufT, sE1, qE1, 2048, 2048);
    k_bn_apply_bf16<<<gsb(2048L * 2048), 256, 0, stream>>>(bufT, sE1, qE1, g_e1, be_e1, enc1_bf, 2048, 2048, 2048, 1.f / 2048);

    XPOSE(W_e2, bufWT, 2048, 256, 256, 2048);
    GEMM(enc1_bf, bufWT, bufT, b_e2, 2048, 256, 256, 2048, 256);           // enc2 raw
    STATS(bufT, sE2, qE2, 2048, 256);
    k_bn_apply_bf16<<<gsb(2048L * 256), 256, 0, stream>>>(bufT, sE2, qE2, g_e2, be_e2, enc_bf, 2048, 256, 256, 1.f / 2048);

    // ---------------- decoder ----------------
    XPOSE(W_d1, bufWT, 256, 2048, 2048, 256);
    GEMM(enc_bf, bufWT, bufT, b_d1, 2048, 2048, 2048, 256, 2048);          // dec1 raw
    STATS(bufT, sD1, qD1, 2048, 2048);
    k_bn_apply_bf16<<<gsb(2048L * 2048), 256, 0, stream>>>(bufT, sD1, qD1, g_d1, be_d1, dec1_bf, 2048, 2048, 2048, 1.f / 2048);

    XPOSE(W_d2, bufWT, 2048, 2476, 2496, 2048);
    GEMM(dec1_bf, bufWT, bufT, b_d2, 2048, 2496, 2476, 2048, 2476);        // dec2 raw
    STATS(bufT, sD2, qD2, 2048, 2476);
    k_bn_apply_f32<<<gsb(2048L * 2476), 256, 0, stream>>>(bufT, sD2, qD2, g_d2, be_d2, outDec, 2048, 2476, 1.f / 2048);

    // ---------------- output head ----------------
    XPOSE(W_o1, bufWT, 256, 64, 64, 256);
    GEMM(enc_bf, bufWT, bufT, b_o1, 2048, 64, 64, 256, 64);                // o1 raw
    STATS(bufT, sO1, qO1, 2048, 64);
    k_bn_apply_f32<<<gsb(2048L * 64), 256, 0, stream>>>(bufT, sO1, qO1, g_o1, be_o1, o1post, 2048, 64, 1.f / 2048);
    k_final_y<<<dim3(512), 256, 0, stream>>>(o1post, W_o2, b_o2, outY, 2048);

    (void)in_sizes; (void)n_in; (void)out_size; (void)ws_size;
}

// Round 3
// 848.530 us; speedup vs baseline: 2.4193x; 1.6171x over previous
//
#include <hip/hip_runtime.h>
#include <hip/hip_bf16.h>

// ---------------------------------------------------------------------------
// GNN forward. R3: GEMM LDS swizzle (pre-swizzled gload source + XOR read),
// stats fused into GEMM epilogue, BN-erased biases dropped, vectorized
// CVT/BN/gather.
// ---------------------------------------------------------------------------

typedef __attribute__((ext_vector_type(8))) short short8v;   // 8 x bf16
typedef __attribute__((ext_vector_type(4))) short short4v;
typedef __attribute__((ext_vector_type(4))) float f32x4;

#define DEV __device__ __forceinline__

DEV short f2bf(float x) {                // RNE f32 -> bf16
    unsigned int u = __float_as_uint(x);
    u += 0x7fffu + ((u >> 16) & 1u);
    return (short)(u >> 16);
}
DEV float bf2f(short v) { return __uint_as_float(((unsigned int)(unsigned short)v) << 16); }
DEV float lrelu(float x) { return x >= 0.f ? x : 0.01f * x; }

DEV void gload_lds16(const short* gp, short* lds_base_uniform) {
    __builtin_amdgcn_global_load_lds(
        (const __attribute__((address_space(1))) unsigned int*)gp,
        (__attribute__((address_space(3))) unsigned int*)lds_base_uniform,
        16, 0, 0);
}

// ---------------- f32 -> bf16 conversions ----------------------------------
__global__ void k_f32_to_bf16_pad(const float* __restrict__ in, short* __restrict__ out,
                                  int R, int C, int Cp) {
    int n = R * Cp;
    for (int i = blockIdx.x * blockDim.x + threadIdx.x; i < n; i += gridDim.x * blockDim.x) {
        int r = i / Cp, c = i - r * Cp;
        out[i] = (c < C) ? f2bf(in[(size_t)r * C + c]) : (short)0;
    }
}

// C==Cp, C%8==0: contiguous 8-wide
__global__ void k_f32_to_bf16_vec(const float* __restrict__ in, short* __restrict__ out, long n8) {
    for (long i = blockIdx.x * blockDim.x + threadIdx.x; i < n8; i += (long)gridDim.x * blockDim.x) {
        const float* p = in + i * 8;
        short8v v;
#pragma unroll
        for (int j = 0; j < 8; ++j) v[j] = f2bf(p[j]);
        *reinterpret_cast<short8v*>(out + i * 8) = v;
    }
}

// ---------------- f32 [R][C] -> bf16 transposed [outR][outC], zero-padded ---
__global__ void k_transpose_bf16(const float* __restrict__ in, short* __restrict__ out,
                                 int R, int C, int outR, int outC) {
    __shared__ float tile[32][33];
    int cb = blockIdx.x * 32, rb = blockIdx.y * 32;
    int tx = threadIdx.x, ty = threadIdx.y;     // 32 x 8
#pragma unroll
    for (int i = 0; i < 32; i += 8) {
        int r = rb + ty + i, c = cb + tx;
        tile[ty + i][tx] = (r < R && c < C) ? in[(size_t)r * C + c] : 0.f;
    }
    __syncthreads();
#pragma unroll
    for (int i = 0; i < 32; i += 8) {
        int oc = cb + ty + i, orr = rb + tx;
        if (oc < outR && orr < outC)
            out[(size_t)oc * outC + orr] = f2bf(tile[tx][ty + i]);
    }
}

// ---------------- GEMM: C[M,N] = A[M,K] @ Bt[N,K]^T ------------------------
// gload_lds staging, LINEAR LDS + pre-swizzled global source; reads XOR the
// same involution (rule #21).  Double-buffered, 1 barrier/K-step.
// Optional fused column stats (sum, sumsq) via shuffle-reduce + atomics.
template<int BM, int BN, bool OBF, bool STATS>
__global__ __launch_bounds__(256)
void k_gemm(const short* __restrict__ A, const short* __restrict__ Bt,
            void* __restrict__ Cout, float* __restrict__ sums, float* __restrict__ sqs,
            int Nreal, int K, int ldc) {
    __shared__ __align__(16) short As[2][BM * 64];
    __shared__ __align__(16) short Bs[2][BN * 64];
    const int tid  = threadIdx.x;
    const int lane = tid & 63, w = tid >> 6;
    const int row0 = blockIdx.x * BM, col0 = blockIdx.y * BN;
    const int wr = w >> 1, wc = w & 1;
    const int lr = lane & 15, lk = lane >> 4;
    const int lrow = lane >> 3;                        // 0..7
    const int lcol = ((lane & 7) ^ lrow) * 8;          // swizzled source chunk
    constexpr int MR = BM / 32, NR = BN / 32;

    f32x4 acc[MR][NR] = {};

    auto stage = [&](int buf, int k0) {
#pragma unroll
        for (int i = 0; i < BM / 32; ++i) {
            int r0 = (w * (BM / 32) + i) * 8;
            gload_lds16(&A[(size_t)(row0 + r0 + lrow) * K + k0 + lcol], &As[buf][r0 * 64]);
        }
#pragma unroll
        for (int i = 0; i < BN / 32; ++i) {
            int r0 = (w * (BN / 32) + i) * 8;
            gload_lds16(&Bt[(size_t)(col0 + r0 + lrow) * K + k0 + lcol], &Bs[buf][r0 * 64]);
        }
    };

    const int nt = K >> 6;
    stage(0, 0);
    __syncthreads();
    for (int t = 0; t < nt; ++t) {
        int cur = t & 1;
        if (t + 1 < nt) stage(cur ^ 1, (t + 1) << 6);
#pragma unroll
        for (int ks = 0; ks < 2; ++ks) {
            short8v a[MR], b[NR];
#pragma unroll
            for (int m = 0; m < MR; ++m) {
                int r = wr * (BM / 2) + m * 16 + lr;
                a[m] = *reinterpret_cast<const short8v*>(
                    &As[cur][r * 64 + ((ks * 32 + lk * 8) ^ ((r & 7) * 8))]);
            }
#pragma unroll
            for (int n = 0; n < NR; ++n) {
                int r = wc * (BN / 2) + n * 16 + lr;
                b[n] = *reinterpret_cast<const short8v*>(
                    &Bs[cur][r * 64 + ((ks * 32 + lk * 8) ^ ((r & 7) * 8))]);
            }
#pragma unroll
            for (int m = 0; m < MR; ++m)
#pragma unroll
                for (int n = 0; n < NR; ++n)
                    acc[m][n] = __builtin_amdgcn_mfma_f32_16x16x32_bf16(a[m], b[n], acc[m][n], 0, 0, 0);
        }
        __syncthreads();
    }
    // epilogue: C/D layout col = lane&15, row = (lane>>4)*4 + j
#pragma unroll
    for (int m = 0; m < MR; ++m) {
#pragma unroll
        for (int n = 0; n < NR; ++n) {
            int col = col0 + wc * (BN / 2) + n * 16 + lr;
            if (col < Nreal) {
#pragma unroll
                for (int j = 0; j < 4; ++j) {
                    int row = row0 + wr * (BM / 2) + m * 16 + lk * 4 + j;
                    float v = acc[m][n][j];
                    if (OBF) ((short*)Cout)[(size_t)row * ldc + col] = f2bf(v);
                    else     ((float*)Cout)[(size_t)row * ldc + col] = v;
                }
            }
        }
    }
    if (STATS) {
#pragma unroll
        for (int n = 0; n < NR; ++n) {
            float s = 0.f, q = 0.f;
#pragma unroll
            for (int m = 0; m < MR; ++m)
#pragma unroll
                for (int j = 0; j < 4; ++j) {
                    float v = acc[m][n][j];
                    s += v; q += v * v;
                }
            s += __shfl_xor(s, 16); s += __shfl_xor(s, 32);
            q += __shfl_xor(q, 16); q += __shfl_xor(q, 32);
            int col = col0 + wc * (BN / 2) + n * 16 + lr;
            if (lane < 16 && col < Nreal) {
                atomicAdd(&sums[col], s);
                atomicAdd(&sqs[col], q);
            }
        }
    }
}

// ---------------- BatchNorm apply (stats already in sums/sqs) --------------
// f32 in -> f32 out, vectorized x4 (C%4==0)
__global__ void k_bn_apply_f32(const float* __restrict__ X, const float* __restrict__ sums,
                               const float* __restrict__ sqs, const float* __restrict__ g,
                               const float* __restrict__ b, float* __restrict__ out,
                               long n4, int C, float invR) {
    for (long i = blockIdx.x * blockDim.x + threadIdx.x; i < n4; i += (long)gridDim.x * blockDim.x) {
        long e0 = i * 4;
        int c0 = (int)(e0 % C);
        f32x4 x = *reinterpret_cast<const f32x4*>(X + e0);
        f32x4 o;
#pragma unroll
        for (int j = 0; j < 4; ++j) {
            int c = c0 + j;
            float m = sums[c] * invR;
            float v = fmaxf(sqs[c] * invR - m * m, 0.f);
            o[j] = lrelu(g[c] * (x[j] - m) * rsqrtf(v + 1e-5f) + b[c]);
        }
        *reinterpret_cast<f32x4*>(out + e0) = o;
    }
}

// f32 in -> bf16 out (C==Cp, C%4==0)
__global__ void k_bn_apply_bf16(const float* __restrict__ X, const float* __restrict__ sums,
                                const float* __restrict__ sqs, const float* __restrict__ g,
                                const float* __restrict__ b, short* __restrict__ out,
                                long n4, int C, float invR) {
    for (long i = blockIdx.x * blockDim.x + threadIdx.x; i < n4; i += (long)gridDim.x * blockDim.x) {
        long e0 = i * 4;
        int c0 = (int)(e0 % C);
        f32x4 x = *reinterpret_cast<const f32x4*>(X + e0);
        short4v o;
#pragma unroll
        for (int j = 0; j < 4; ++j) {
            int c = c0 + j;
            float m = sums[c] * invR;
            float v = fmaxf(sqs[c] * invR - m * m, 0.f);
            o[j] = f2bf(lrelu(g[c] * (x[j] - m) * rsqrtf(v + 1e-5f) + b[c]));
        }
        *reinterpret_cast<short4v*>(out + e0) = o;
    }
}

// ---------------- conv path (algebraic) ------------------------------------
__global__ void k_build_wp_bf(const float* __restrict__ Wc, short* __restrict__ Wp) {
    int i = blockIdx.x * blockDim.x + threadIdx.x;
    if (i >= 1024 * 256) return;
    int c = i >> 8, j = i & 255, o = j >> 3, kh = j & 7;
    Wp[i] = (c < 1000) ? f2bf(Wc[o * 8000 + c * 8 + kh]) : (short)0;
}

__global__ __launch_bounds__(256)
void k_build_m2t(const float* __restrict__ emb, const float* __restrict__ W_fc,
                 short* __restrict__ M2t) {
    int s = blockIdx.x >> 5, o = blockIdx.x & 31;   // 26*32 blocks
    __shared__ float embS[128];
    int t = threadIdx.x;
    if (t < 128) embS[t] = emb[s * 128 + t];
    __syncthreads();
    int f = t & 127;
    int khBase = (t >> 7) * 4;
#pragma unroll
    for (int i = 0; i < 4; ++i) {
        int kh = khBase + i;
        float acc = 0.f;
        for (int h = 0; h < 121; ++h)
            acc += embS[h + kh] * W_fc[(o * 121 + h) * 128 + f];
        M2t[((size_t)(s * 128 + f)) * 256 + o * 8 + kh] = f2bf(acc);
    }
}

__global__ void k_build_cf(const float* __restrict__ W_fc, const float* __restrict__ b_conv,
                           float* __restrict__ Cf) {
    int o = blockIdx.x, f = threadIdx.x;   // 32 blocks x 128
    float acc = 0.f;
    for (int h = 0; h < 121; ++h) acc += W_fc[(o * 121 + h) * 128 + f];
    atomicAdd(&Cf[f], acc * b_conv[o]);
}

// xt[b][f] = b_fc[f] + Cf[f] + sum_c Rbf[c][pemb[b,c]*128+f]; 2 bf16/lane
__global__ __launch_bounds__(256)
void k_gather_xt(const int* __restrict__ pemb, const short* __restrict__ Rbf,
                 const float* __restrict__ Cf, const float* __restrict__ b_fc,
                 float* __restrict__ xt) {
    const int b = blockIdx.x, t = threadIdx.x;
    __shared__ int sS[1000];
    __shared__ float red[512];
    for (int c = t; c < 1000; c += 256) sS[c] = pemb[b * 1000 + c];
    __syncthreads();
    const int f2 = t & 63;                  // pair index: f = f2*2, f2*2+1
    const int q = t >> 6;                   // quarter 0..3
    float a0 = 0.f, a1 = 0.f;
    const int c0 = q * 250;
#pragma unroll 2
    for (int c = c0; c < c0 + 250; ++c) {
        int s = sS[c];
        unsigned int u = *reinterpret_cast<const unsigned int*>(
            &Rbf[((size_t)c * 26 + s) * 128 + f2 * 2]);
        a0 += __uint_as_float(u << 16);
        a1 += __uint_as_float(u & 0xffff0000u);
    }
    red[t * 2]     = a0;
    red[t * 2 + 1] = a1;
    __syncthreads();
    if (t < 128) {
        int fq = t >> 1, comp = t & 1;      // reconstruct f = fq*2+comp
        float v = red[(0 * 64 + fq) * 2 + comp] + red[(1 * 64 + fq) * 2 + comp]
                + red[(2 * 64 + fq) * 2 + comp] + red[(3 * 64 + fq) * 2 + comp];
        int f = fq * 2 + comp;
        xt[b * 128 + f] = v + Cf[f] + b_fc[f];
    }
}

// ---------------- feature assembly ----------------------------------------
__global__ void k_assemble(const float* __restrict__ d_vecs, const float* __restrict__ E,
                           const float* __restrict__ xt, const float* __restrict__ G,
                           const int* __restrict__ d_index, const int* __restrict__ p_index,
                           float* __restrict__ feat) {
    int n = 2048 * 2476;
    for (int i = blockIdx.x * blockDim.x + threadIdx.x; i < n; i += gridDim.x * blockDim.x) {
        int b = i / 2476, c = i - b * 2476;
        float v;
        if (c < 300)        v = d_vecs[b * 300 + c];
        else if (c < 1324)  v = E[(size_t)d_index[b] * 1024 + (c - 300)];
        else if (c < 1452)  v = xt[b * 128 + (c - 1324)];
        else                v = G[(size_t)p_index[b] * 1024 + (c - 1452)];
        feat[i] = v;
    }
}

// ---------------- final y = o1post @ W_o2 + b_o2 ---------------------------
__global__ void k_final_y(const float* __restrict__ o1post, const float* __restrict__ W_o2,
                          const float* __restrict__ b_o2, float* __restrict__ y, int B) {
    int gt = blockIdx.x * blockDim.x + threadIdx.x;
    int wid = gt >> 6, lane = gt & 63;
    if (wid >= B) return;
    float v = o1post[wid * 64 + lane] * W_o2[lane];
#pragma unroll
    for (int off = 32; off; off >>= 1) v += __shfl_down(v, off);
    if (lane == 0) y[wid] = v + b_o2[0];
}

// ===========================================================================
extern "C" void kernel_launch(void* const* d_in, const int* in_sizes, int n_in,
                              void* d_out, int out_size, void* d_ws, size_t ws_size,
                              hipStream_t stream) {
    const int*   d_index = (const int*)  d_in[0];
    const int*   p_index = (const int*)  d_in[1];
    const int*   p_emb   = (const int*)  d_in[2];
    const float* d_vecs  = (const float*)d_in[3];
    const float* d_ecfps = (const float*)d_in[4];
    const float* d_ew    = (const float*)d_in[5];
    const float* p_gos   = (const float*)d_in[6];
    const float* p_ew    = (const float*)d_in[7];
    const float* emb     = (const float*)d_in[8];
    const float* W_ge    = (const float*)d_in[9];
    const float* W_gg    = (const float*)d_in[11];
    const float* g_n1    = (const float*)d_in[13];
    const float* b_n1    = (const float*)d_in[14];
    const float* W_conv  = (const float*)d_in[15];
    const float* b_conv  = (const float*)d_in[16];
    const float* W_fc    = (const float*)d_in[17];
    const float* b_fc    = (const float*)d_in[18];
    const float* W_e1    = (const float*)d_in[19];
    const float* g_e1    = (const float*)d_in[21];
    const float* be_e1   = (const float*)d_in[22];
    const float* W_e2    = (const float*)d_in[23];
    const float* g_e2    = (const float*)d_in[25];
    const float* be_e2   = (const float*)d_in[26];
    const float* W_d1    = (const float*)d_in[27];
    const float* g_d1    = (const float*)d_in[29];
    const float* be_d1   = (const float*)d_in[30];
    const float* W_d2    = (const float*)d_in[31];
    const float* g_d2    = (const float*)d_in[33];
    const float* be_d2   = (const float*)d_in[34];
    const float* W_o1    = (const float*)d_in[35];
    const float* g_o1    = (const float*)d_in[37];
    const float* be_o1   = (const float*)d_in[38];
    const float* W_o2    = (const float*)d_in[39];
    const float* b_o2    = (const float*)d_in[40];

    float* outY    = (float*)d_out;
    float* outDec  = outY + 2048;
    float* outFeat = outDec + (size_t)2048 * 2476;

    char* W = (char*)d_ws;
    size_t cur = 0;
    auto take = [&](size_t bytes) -> size_t {
        size_t r = cur; cur += (bytes + 255) & ~(size_t)255; return r;
    };
    float* stats   = (float*)(W + take(18008 * 4));
    short* bufX    = (short*)(W + take((size_t)4096 * 2048 * 2));
    short* ew_bf   = (short*)(W + take((size_t)4096 * 4096 * 2));
    short* feat_bf = (short*)(W + take((size_t)2048 * 2496 * 2));
    short* enc1_bf = (short*)(W + take((size_t)2048 * 2048 * 2));
    short* enc_bf  = (short*)(W + take((size_t)2048 * 256 * 2));
    short* dec1_bf = (short*)(W + take((size_t)2048 * 2048 * 2));
    short* bufWT   = (short*)(W + take((size_t)2560 * 2048 * 2));
    float* bufT    = (float*)(W + take((size_t)2048 * 2476 * 4));
    float* bufE    = (float*)(W + take((size_t)4096 * 1024 * 4));
    float* bufG    = (float*)(W + take((size_t)4096 * 1024 * 4));
    float* xt      = (float*)(W + take((size_t)2048 * 128 * 4));
    float* o1post  = (float*)(W + take((size_t)2048 * 64 * 4));
    short* Wp_bf   = (short*)(W + take((size_t)1024 * 256 * 2));
    short* M2t     = (short*)(W + take((size_t)3328 * 256 * 2));
    short* Rbf     = (short*)(W + take((size_t)1024 * 3328 * 2));

    float* sD  = stats,        *qD  = sD + 1024;
    float* sP  = qD + 1024,    *qP  = sP + 1024;
    float* sE1 = qP + 1024,    *qE1 = sE1 + 2048;
    float* sE2 = qE1 + 2048,   *qE2 = sE2 + 256;
    float* sD1 = qE2 + 256,    *qD1 = sD1 + 2048;
    float* sD2 = qD1 + 2048,   *qD2 = sD2 + 2476;
    float* sO1 = qD2 + 2476,   *qO1 = sO1 + 64;
    float* Cf  = qO1 + 64;
    hipMemsetAsync(stats, 0, 18008 * 4, stream);

    auto gsb = [](long n) { long b = (n + 255) / 256; if (b > 4096) b = 4096; return dim3((unsigned)b); };
    auto CVTV = [&](const float* in, short* out, long nelem) {
        k_f32_to_bf16_vec<<<gsb(nelem / 8), 256, 0, stream>>>(in, out, nelem / 8);
    };
    auto XPOSE = [&](const float* in, short* out, int R, int C, int oR, int oC) {
        k_transpose_bf16<<<dim3(oR / 32, oC / 32), dim3(32, 8), 0, stream>>>(in, out, R, C, oR, oC);
    };
    // plain GEMM (f32 out, no stats)
    auto GEMM = [&](const short* A, const short* Bt, float* Co,
                    int M, int Npad, int Nreal, int K, int ldc) {
        k_gemm<128, 64, false, false><<<dim3(M / 128, Npad / 64), 256, 0, stream>>>(
            A, Bt, Co, nullptr, nullptr, Nreal, K, ldc);
    };
    // GEMM + fused column stats
    auto GEMMS = [&](const short* A, const short* Bt, float* Co, float* s, float* q,
                     int M, int Npad, int Nreal, int K, int ldc) {
        k_gemm<128, 64, false, true><<<dim3(M / 128, Npad / 64), 256, 0, stream>>>(
            A, Bt, Co, s, q, Nreal, K, ldc);
    };
    auto BNF = [&](const float* X, const float* s, const float* q, const float* g,
                   const float* be, float* out, long R, long C) {
        k_bn_apply_f32<<<gsb(R * C / 4), 256, 0, stream>>>(X, s, q, g, be, out, R * C / 4, (int)C, 1.f / R);
    };
    auto BNB = [&](const float* X, const float* s, const float* q, const float* g,
                   const float* be, short* out, long R, long C) {
        k_bn_apply_bf16<<<gsb(R * C / 4), 256, 0, stream>>>(X, s, q, g, be, out, R * C / 4, (int)C, 1.f / R);
    };

    // ---------------- conv path (independent; launch first) ----------------
    k_build_wp_bf<<<dim3(1024), 256, 0, stream>>>(W_conv, Wp_bf);
    k_build_m2t<<<dim3(26 * 32), 256, 0, stream>>>(emb, W_fc, M2t);
    k_build_cf<<<dim3(32), 128, 0, stream>>>(W_fc, b_conv, Cf);
    k_gemm<128, 64, true, false><<<dim3(1024 / 128, 3328 / 64), 256, 0, stream>>>(
        Wp_bf, M2t, (void*)Rbf, nullptr, nullptr, 3328, 256, 3328);
    k_gather_xt<<<dim3(2048), 256, 0, stream>>>(p_emb, Rbf, Cf, b_fc, xt);

    // ---------------- drug GCN (biases erased by BN) ----------------
    CVTV(d_ecfps, bufX, 4096L * 1024);
    XPOSE(W_ge, bufWT, 1024, 1024, 1024, 1024);
    GEMM(bufX, bufWT, bufT, 4096, 1024, 1024, 1024, 1024);                  // T1
    XPOSE(bufT, bufWT, 4096, 1024, 1024, 4096);
    CVTV(d_ew, ew_bf, 4096L * 4096);
    GEMMS(ew_bf, bufWT, bufE, sD, qD, 4096, 1024, 1024, 4096, 1024);        // T2
    BNF(bufE, sD, qD, g_n1, b_n1, bufE, 4096, 1024);

    // ---------------- protein GCN ----------------
    CVTV(p_gos, bufX, 4096L * 2048);
    XPOSE(W_gg, bufWT, 2048, 1024, 1024, 2048);
    GEMM(bufX, bufWT, bufT, 4096, 1024, 1024, 2048, 1024);                  // T3
    XPOSE(bufT, bufWT, 4096, 1024, 1024, 4096);
    CVTV(p_ew, ew_bf, 4096L * 4096);
    GEMMS(ew_bf, bufWT, bufG, sP, qP, 4096, 1024, 1024, 4096, 1024);        // T4
    BNF(bufG, sP, qP, g_n1, b_n1, bufG, 4096, 1024);

    // ---------------- feature ----------------
    k_assemble<<<gsb(2048L * 2476), 256, 0, stream>>>(d_vecs, bufE, xt, bufG, d_index, p_index, outFeat);
    k_f32_to_bf16_pad<<<gsb(2048L * 2496), 256, 0, stream>>>(outFeat, feat_bf, 2048, 2476, 2496);

    // ---------------- encoder ----------------
    XPOSE(W_e1, bufWT, 2476, 2048, 2048, 2496);
    GEMMS(feat_bf, bufWT, bufT, sE1, qE1, 2048, 2048, 2048, 2496, 2048);    // enc1
    BNB(bufT, sE1, qE1, g_e1, be_e1, enc1_bf, 2048, 2048);

    XPOSE(W_e2, bufWT, 2048, 256, 256, 2048);
    GEMMS(enc1_bf, bufWT, bufT, sE2, qE2, 2048, 256, 256, 2048, 256);       // enc2
    BNB(bufT, sE2, qE2, g_e2, be_e2, enc_bf, 2048, 256);

    // ---------------- decoder ----------------
    XPOSE(W_d1, bufWT, 256, 2048, 2048, 256);
    GEMMS(enc_bf, bufWT, bufT, sD1, qD1, 2048, 2048, 2048, 256, 2048);      // dec1
    BNB(bufT, sD1, qD1, g_d1, be_d1, dec1_bf, 2048, 2048);

    XPOSE(W_d2, bufWT, 2048, 2476, 2496, 2048);
    GEMMS(dec1_bf, bufWT, bufT, sD2, qD2, 2048, 2496, 2476, 2048, 2476);    // dec2
    BNF(bufT, sD2, qD2, g_d2, be_d2, outDec, 2048, 2476);

    // ---------------- output head ----------------
    XPOSE(W_o1, bufWT, 256, 64, 64, 256);
    GEMMS(enc_bf, bufWT, bufT, sO1, qO1, 2048, 64, 64, 256, 64);            // o1
    BNF(bufT, sO1, qO1, g_o1, be_o1, o1post, 2048, 64);
    k_final_y<<<dim3(512), 256, 0, stream>>>(o1post, W_o2, b_o2, outY, 2048);

    (void)in_sizes; (void)n_in; (void)out_size; (void)ws_size;
}